// Round 5
// baseline (75.495 us; speedup 1.0000x reference)
//
#include <hip/hip_runtime.h>

// Problem constants
#define RES    128
#define P_PTS  4096
#define CHUNKS 32
#define PP     128          // trajectory points per chunk

// Workspace: part half2 [32][1024*128] = 16 MB at offset 0
typedef _Float16 half8  __attribute__((ext_vector_type(8)));
typedef _Float16 half2v __attribute__((ext_vector_type(2)));
typedef float    f32x4  __attribute__((ext_vector_type(4)));

// ---------------------------------------------------------------------------
// fused gemm: grid (32 chunks, 16 = b*2+mh) = 512 blocks (2/CU, 2 waves/SIMD).
// Per block: cache traj + grid-sampled c for its 128 p's in LDS, then
// 4 rounds of {generate sA/sB tile (32 p) in LDS via v_sin/v_cos, MFMA},
// double-buffered LDS -> ONE barrier per round.
// Block tile M64 x N128, wave tile M64 x N32, 4x2 mfma_f32_16x16x32_f16 (R+I).
// ---------------------------------------------------------------------------
__global__ __launch_bounds__(256) void gemm_kernel(const float* __restrict__ ksp,
                                                   const float* __restrict__ traj,
                                                   half2v* __restrict__ part) {
    __shared__ float stx[PP], sty[PP];              // trajectory per p
    __shared__ float2 sc[PP];                       // c[b,p]/128
    __shared__ __align__(16) _Float16 sA[2][4096];  // [buf][k8l(8)][m(64)][8]
    __shared__ __align__(16) _Float16 sB[2][8192];  // [buf][k8l(8)][n(128)][8]

    const int chunk = blockIdx.x;          // 0..31
    const int b     = blockIdx.y >> 1;     // 0..7
    const int mh    = blockIdx.y & 1;      // 0..1
    const int tid   = threadIdx.x;
    const int wave  = tid >> 6;
    const int lane  = tid & 63;
    const int l15   = lane & 15;
    const int q     = lane >> 4;

    // ---- setup: traj slice + bilinear grid-sample (one p per thread) ----
    if (tid < PP) {
        const int p = chunk * PP + tid;
        const float tx = traj[2 * p], ty = traj[2 * p + 1];
        stx[tid] = tx;
        sty[tid] = ty;
        const float x = tx + 63.5f, y = ty + 63.5f;
        const float x0f = floorf(x), y0f = floorf(y);
        const float wx = x - x0f, wy = y - y0f;
        const int ix0 = (int)x0f, iy0 = (int)y0f;
        float re = 0.0f, im = 0.0f;
#pragma unroll
        for (int dy = 0; dy < 2; ++dy) {
#pragma unroll
            for (int dx = 0; dx < 2; ++dx) {
                const int ix = ix0 + dx, iy = iy0 + dy;
                const float w = (dx ? wx : 1.0f - wx) * (dy ? wy : 1.0f - wy);
                if (ix >= 0 && ix < RES && iy >= 0 && iy < RES) {
                    const float2 v = *(const float2*)(ksp + ((b * RES + iy) * RES + ix) * 2);
                    re = fmaf(v.x, w, re);
                    im = fmaf(v.y, w, im);
                }
            }
        }
        sc[tid] = make_float2(re * (1.0f / 128.0f), im * (1.0f / 128.0f));
    }
    __syncthreads();

    f32x4 accR[4][2], accI[4][2];
#pragma unroll
    for (int i = 0; i < 4; ++i)
#pragma unroll
        for (int j = 0; j < 2; ++j) {
            accR[i][j] = (f32x4){0.f, 0.f, 0.f, 0.f};
            accI[i][j] = (f32x4){0.f, 0.f, 0.f, 0.f};
        }

    const float inv = 1.0f / 128.0f;
    const int nB = tid & 127, kB = tid >> 7;    // B-gen: k8l = kB + 2i
    const int mA = tid & 63,  kA = tid >> 6;    // A-gen: k8l = kA + 4i
    const float xn = ((float)nB - 64.0f) * inv;
    const float xm = ((float)(mh * 64 + mA) - 64.0f) * inv;

    for (int r = 0; r < 4; ++r) {
        const int p0  = r * 32;
        const int buf = r & 1;
        // ---- generate B tile: Ax phasors ----
#pragma unroll
        for (int i = 0; i < 4; ++i) {
            const int k8l = kB + 2 * i;
            half8 v;
#pragma unroll
            for (int j = 0; j < 4; ++j) {
                const int pl = p0 + k8l * 4 + j;       // wave-uniform -> broadcast
                const float rev = stx[pl] * xn;
                const float f = rev - floorf(rev);
                v[2 * j]     = (_Float16)__builtin_amdgcn_cosf(f);
                v[2 * j + 1] = (_Float16)__builtin_amdgcn_sinf(f);
            }
            *(half8*)(&sB[buf][(k8l * 128 + nB) * 8]) = v;
        }
        // ---- generate A tile: c-folded Ay phasors ----
#pragma unroll
        for (int i = 0; i < 2; ++i) {
            const int k8l = kA + 4 * i;
            half8 v;
#pragma unroll
            for (int j = 0; j < 4; ++j) {
                const int pl = p0 + k8l * 4 + j;
                const float rev = sty[pl] * xm;
                const float f = rev - floorf(rev);
                const float cs = __builtin_amdgcn_cosf(f);
                const float sn = __builtin_amdgcn_sinf(f);
                const float cr = sc[pl].x, ci = sc[pl].y;
                v[2 * j]     = (_Float16)(cr * cs - ci * sn);
                v[2 * j + 1] = (_Float16)(cr * sn + ci * cs);
            }
            *(half8*)(&sA[buf][(k8l * 64 + mA) * 8]) = v;
        }
        __syncthreads();   // single barrier: writes(buf) -> reads(buf)

        // ---- MFMA on the tile ----
#pragma unroll
        for (int s = 0; s < 2; ++s) {
            const _Float16* pa = &sA[buf][(s * 4 + q) * 512];
            const _Float16* pb = &sB[buf][(s * 4 + q) * 1024];
            half8 an[4], bv[2], a1[4], a2[4];
#pragma unroll
            for (int mt = 0; mt < 4; ++mt)
                an[mt] = *(const half8*)(pa + (mt * 16 + l15) * 8);
#pragma unroll
            for (int nt = 0; nt < 2; ++nt)
                bv[nt] = *(const half8*)(pb + (wave * 32 + nt * 16 + l15) * 8);
            const half8 SGN = {(_Float16)1.f, (_Float16)-1.f, (_Float16)1.f, (_Float16)-1.f,
                               (_Float16)1.f, (_Float16)-1.f, (_Float16)1.f, (_Float16)-1.f};
#pragma unroll
            for (int mt = 0; mt < 4; ++mt) {
                a1[mt] = an[mt] * SGN;                                     // (ar,-ai)
                a2[mt] = __builtin_shufflevector(an[mt], an[mt],
                                                 1, 0, 3, 2, 5, 4, 7, 6); // (ai,ar)
            }
#pragma unroll
            for (int mt = 0; mt < 4; ++mt)
#pragma unroll
                for (int nt = 0; nt < 2; ++nt) {
                    accR[mt][nt] = __builtin_amdgcn_mfma_f32_16x16x32_f16(
                        a1[mt], bv[nt], accR[mt][nt], 0, 0, 0);
                    accI[mt][nt] = __builtin_amdgcn_mfma_f32_16x16x32_f16(
                        a2[mt], bv[nt], accI[mt][nt], 0, 0, 0);
                }
        }
        // no second barrier: next round writes the other LDS buffer
    }

    // ---- epilogue: C/D layout col=lane&15, row=q*4+reg ----
#pragma unroll
    for (int mt = 0; mt < 4; ++mt) {
#pragma unroll
        for (int nt = 0; nt < 2; ++nt) {
            const int n = wave * 32 + nt * 16 + l15;
#pragma unroll
            for (int rg = 0; rg < 4; ++rg) {
                const int m = b * 128 + mh * 64 + mt * 16 + q * 4 + rg;
                half2v pv;
                pv[0] = (_Float16)accR[mt][nt][rg];
                pv[1] = (_Float16)accI[mt][nt][rg];
                part[(size_t)chunk * 131072 + m * 128 + n] = pv;
            }
        }
    }
}

// ---------------------------------------------------------------------------
// reduce: sum 32 fp16 partials in fp32 -> out (B,1,128,128,2) fp32
// ---------------------------------------------------------------------------
__global__ __launch_bounds__(256) void reduce_kernel(const half2v* __restrict__ part,
                                                     float2* __restrict__ out) {
    const int i = blockIdx.x * 256 + threadIdx.x;   // 0..131071
    float sr = 0.f, si = 0.f;
#pragma unroll
    for (int c = 0; c < CHUNKS; ++c) {
        half2v v = part[(size_t)c * 131072 + i];
        sr += (float)v[0];
        si += (float)v[1];
    }
    out[i] = make_float2(sr, si);
}

// ---------------------------------------------------------------------------
extern "C" void kernel_launch(void* const* d_in, const int* in_sizes, int n_in,
                              void* d_out, int out_size, void* d_ws, size_t ws_size,
                              hipStream_t stream) {
    const float* ksp  = (const float*)d_in[0];   // (B,1,128,128,2) fp32
    const float* traj = (const float*)d_in[1];   // (4096,2) fp32
    half2v* part = (half2v*)d_ws;

    hipLaunchKernelGGL(gemm_kernel,   dim3(CHUNKS, 16), dim3(256), 0, stream,
                       ksp, traj, part);
    hipLaunchKernelGGL(reduce_kernel, dim3(512),        dim3(256), 0, stream,
                       part, (float2*)d_out);
}